// Round 2
// baseline (1864.272 us; speedup 1.0000x reference)
//
#include <hip/hip_runtime.h>

enum { TT = 2048, HH = 64, BB = 64, GG = 256, VV = 256 };

// ---------------- K1: embW[v][g] = emb[v]·w_ih[g] + b_ih[g] + b_hh[g] ----------------
__global__ __launch_bounds__(256) void k_embw(const float* __restrict__ emb,
                                              const float* __restrict__ w_ih,
                                              const float* __restrict__ b_ih,
                                              const float* __restrict__ b_hh,
                                              float* __restrict__ embW){
  int v = blockIdx.x, g = threadIdx.x;
  __shared__ float e[HH];
  if (g < HH) e[g] = emb[v*HH + g];
  __syncthreads();
  float acc = b_ih[g] + b_hh[g];
  const float* wr = w_ih + g*HH;
#pragma unroll
  for (int k = 0; k < HH; k += 4){
    float4 w4 = *(const float4*)(wr + k);
    acc = fmaf(e[k],   w4.x, acc); acc = fmaf(e[k+1], w4.y, acc);
    acc = fmaf(e[k+2], w4.z, acc); acc = fmaf(e[k+3], w4.w, acc);
  }
  embW[v*GG + g] = acc;
}

// ---------------- K2: LSTM, one workgroup per batch row ----------------
__global__ __launch_bounds__(256) void k_lstm(const int* __restrict__ x,
                                              const float* __restrict__ embW,
                                              const float* __restrict__ w_hh,
                                              float* __restrict__ hout){
  int b = blockIdx.x, g = threadIdx.x;
  __shared__ float hsh[HH];
  __shared__ float gsh[GG];
  float w[HH];
  {
    const float* wr = w_hh + g*HH;
#pragma unroll
    for (int k = 0; k < HH; k += 4)
      *(float4*)&w[k] = *(const float4*)(wr + k);
  }
  if (g < HH) hsh[g] = 0.f;
  float c = 0.f;
  const int* xb = x + b*TT;
  int i0 = xb[0];
  float gx = embW[i0*GG + g];          // gates(x) for t=0
  int i1 = xb[1];
  const bool istanh = ((g >> 6) == 2); // wave 2 = g-gate (tanh); wave-uniform branch
  __syncthreads();
  for (int t = 0; t < TT; t++){
    float gxn = embW[i1*GG + g];                       // prefetch t+1 (coalesced 1KB)
    int inx = xb[(t + 2 < TT) ? (t + 2) : (TT - 1)];   // prefetch index t+2
    float acc = gx;
#pragma unroll
    for (int k = 0; k < HH; k += 4){
      float4 h4 = *(const float4*)&hsh[k];             // broadcast ds_read_b128
      acc = fmaf(w[k],   h4.x, acc); acc = fmaf(w[k+1], h4.y, acc);
      acc = fmaf(w[k+2], h4.z, acc); acc = fmaf(w[k+3], h4.w, acc);
    }
    float val;
    if (istanh) val = 1.f - 2.f/(__expf(2.f*acc) + 1.f);
    else        val = 1.f/(1.f + __expf(-acc));
    gsh[g] = val;
    __syncthreads();
    if (g < HH){
      float i_ = gsh[g], f_ = gsh[HH+g], gg = gsh[128+g], o_ = gsh[192+g];
      c = fmaf(f_, c, i_*gg);
      float th = 1.f - 2.f/(__expf(2.f*c) + 1.f);
      float hv = o_*th;
      hsh[g] = hv;
      hout[(size_t)(b*TT + t)*HH + g] = hv;
    }
    __syncthreads();
    gx = gxn; i1 = inx;
  }
}

// ---------------- K3: fused MHA level, one workgroup per time step t ----------------
// attention is over the batch axis (64x64 per (t, head)); all staging in LDS (64KB)
__global__ __launch_bounds__(256) void k_mha(const float* __restrict__ hin,
                                             const float* __restrict__ wqkv,
                                             const float* __restrict__ bqkv,
                                             const float* __restrict__ wo,
                                             const float* __restrict__ bo,
                                             float* __restrict__ hout){
  int t = blockIdx.x, tid = threadIdx.x;
  __shared__ float xta[BB][HH];    // x column, later reused for attention output (16KB)
  __shared__ float qkvs[BB][192];  // qkv rows (48KB)

  // stage-2 weights (threads 0..191 own one output feature row)
  float wq[HH]; float bq = 0.f;
  if (tid < 192){
#pragma unroll
    for (int k = 0; k < HH; k += 4)
      *(float4*)&wq[k] = *(const float4*)(wqkv + tid*HH + k);
    bq = bqkv[tid];
  }
  // stage 1: load x[:, t, :] (64 rows x 64 fp32); thread loads 16 floats
  {
    int r = tid >> 2, q = tid & 3;
    const float* p = hin + (size_t)(r*TT + t)*HH + q*16;
#pragma unroll
    for (int j = 0; j < 16; j += 4)
      *(float4*)&xta[r][q*16 + j] = *(const float4*)(p + j);
  }
  __syncthreads();
  // stage 2: qkv = x @ wqkv^T + bqkv
  if (tid < 192){
#pragma unroll 4
    for (int b = 0; b < BB; b++){
      float acc = bq;
#pragma unroll
      for (int k = 0; k < HH; k += 4){
        float4 xv = *(const float4*)&xta[b][k];        // broadcast
        acc = fmaf(wq[k],   xv.x, acc); acc = fmaf(wq[k+1], xv.y, acc);
        acc = fmaf(wq[k+2], xv.z, acc); acc = fmaf(wq[k+3], xv.w, acc);
      }
      qkvs[b][tid] = acc;
    }
  }
  __syncthreads();
  // stage 3: attention; thread (head hd = wave, row l = lane)
  {
    int hd = tid >> 6, l = tid & 63;
    int qo = hd*16, ko = 64 + hd*16, vo = 128 + hd*16;
    float4 q0 = *(const float4*)&qkvs[l][qo];
    float4 q1 = *(const float4*)&qkvs[l][qo+4];
    float4 q2 = *(const float4*)&qkvs[l][qo+8];
    float4 q3 = *(const float4*)&qkvs[l][qo+12];
    float S[BB];
#pragma unroll
    for (int m = 0; m < BB; m++){
      float4 k0 = *(const float4*)&qkvs[m][ko];
      float4 k1 = *(const float4*)&qkvs[m][ko+4];
      float4 k2 = *(const float4*)&qkvs[m][ko+8];
      float4 k3 = *(const float4*)&qkvs[m][ko+12];
      float d;
      d = q0.x*k0.x;         d = fmaf(q0.y,k0.y,d); d = fmaf(q0.z,k0.z,d); d = fmaf(q0.w,k0.w,d);
      d = fmaf(q1.x,k1.x,d); d = fmaf(q1.y,k1.y,d); d = fmaf(q1.z,k1.z,d); d = fmaf(q1.w,k1.w,d);
      d = fmaf(q2.x,k2.x,d); d = fmaf(q2.y,k2.y,d); d = fmaf(q2.z,k2.z,d); d = fmaf(q2.w,k2.w,d);
      d = fmaf(q3.x,k3.x,d); d = fmaf(q3.y,k3.y,d); d = fmaf(q3.z,k3.z,d); d = fmaf(q3.w,k3.w,d);
      S[m] = 0.25f*d;
    }
    float mx = S[0];
#pragma unroll
    for (int m = 1; m < BB; m++) mx = fmaxf(mx, S[m]);
    float sum = 0.f;
#pragma unroll
    for (int m = 0; m < BB; m++){ S[m] = __expf(S[m] - mx); sum += S[m]; }
    float inv = 1.f/sum;
    float4 a0 = make_float4(0,0,0,0), a1 = a0, a2 = a0, a3 = a0;
#pragma unroll
    for (int m = 0; m < BB; m++){
      float s = S[m];
      float4 v0 = *(const float4*)&qkvs[m][vo];
      float4 v1 = *(const float4*)&qkvs[m][vo+4];
      float4 v2 = *(const float4*)&qkvs[m][vo+8];
      float4 v3 = *(const float4*)&qkvs[m][vo+12];
      a0.x = fmaf(s,v0.x,a0.x); a0.y = fmaf(s,v0.y,a0.y); a0.z = fmaf(s,v0.z,a0.z); a0.w = fmaf(s,v0.w,a0.w);
      a1.x = fmaf(s,v1.x,a1.x); a1.y = fmaf(s,v1.y,a1.y); a1.z = fmaf(s,v1.z,a1.z); a1.w = fmaf(s,v1.w,a1.w);
      a2.x = fmaf(s,v2.x,a2.x); a2.y = fmaf(s,v2.y,a2.y); a2.z = fmaf(s,v2.z,a2.z); a2.w = fmaf(s,v2.w,a2.w);
      a3.x = fmaf(s,v3.x,a3.x); a3.y = fmaf(s,v3.y,a3.y); a3.z = fmaf(s,v3.z,a3.z); a3.w = fmaf(s,v3.w,a3.w);
    }
    a0.x*=inv; a0.y*=inv; a0.z*=inv; a0.w*=inv;
    a1.x*=inv; a1.y*=inv; a1.z*=inv; a1.w*=inv;
    a2.x*=inv; a2.y*=inv; a2.z*=inv; a2.w*=inv;
    a3.x*=inv; a3.y*=inv; a3.z*=inv; a3.w*=inv;
    __syncthreads();   // ensure stage-2 readers of xta are done before overwrite
    // xta reused for attention output
    *(float4*)&xta[l][qo]    = a0;
    *(float4*)&xta[l][qo+4]  = a1;
    *(float4*)&xta[l][qo+8]  = a2;
    *(float4*)&xta[l][qo+12] = a3;
  }
  __syncthreads();
  // stage 4: out projection; thread owns col c for 16 rows
  {
    int c = tid & 63, wg = tid >> 6;
    float wor[HH];
#pragma unroll
    for (int k = 0; k < HH; k += 4)
      *(float4*)&wor[k] = *(const float4*)(wo + c*HH + k);
    float bo4 = bo[c];
#pragma unroll 2
    for (int j = 0; j < 16; j++){
      int b = wg*16 + j;
      float acc = bo4;
#pragma unroll
      for (int k = 0; k < HH; k += 4){
        float4 xv = *(const float4*)&xta[b][k];        // broadcast
        acc = fmaf(wor[k],   xv.x, acc); acc = fmaf(wor[k+1], xv.y, acc);
        acc = fmaf(wor[k+2], xv.z, acc); acc = fmaf(wor[k+3], xv.w, acc);
      }
      hout[(size_t)(b*TT + t)*HH + c] = acc;
    }
  }
}

// ---------------- K4: LayerNorm + FC (ln folded into fc_w registers) ----------------
__global__ __launch_bounds__(256) void k_fc(const float* __restrict__ hin,
                                            const float* __restrict__ ln_g,
                                            const float* __restrict__ ln_b,
                                            const float* __restrict__ fc_w,
                                            const float* __restrict__ fc_b,
                                            float* __restrict__ out){
  int tid = threadIdx.x;
  __shared__ float tile[64][68];
  __shared__ float ps[64][4];
  __shared__ float pq[64][4];
  __shared__ float mu[64], rs[64];
  float w[HH];
  float wsum = 0.f, bias2 = fc_b[tid];
#pragma unroll
  for (int k = 0; k < HH; k += 4){
    float4 wv = *(const float4*)(fc_w + tid*HH + k);
    float4 gv = *(const float4*)(ln_g + k);
    float4 bv = *(const float4*)(ln_b + k);
    bias2 = fmaf(bv.x, wv.x, bias2); bias2 = fmaf(bv.y, wv.y, bias2);
    bias2 = fmaf(bv.z, wv.z, bias2); bias2 = fmaf(bv.w, wv.w, bias2);
    w[k]   = gv.x*wv.x; w[k+1] = gv.y*wv.y;
    w[k+2] = gv.z*wv.z; w[k+3] = gv.w*wv.w;
    wsum += w[k] + w[k+1] + w[k+2] + w[k+3];
  }
  int r = tid >> 2, q = tid & 3;
  for (int ti = 0; ti < 4; ti++){
    int rowbase = blockIdx.x*256 + ti*64;
    const float* p = hin + (size_t)(rowbase + r)*HH + q*16;
    float xv[16];
#pragma unroll
    for (int j = 0; j < 16; j += 4)
      *(float4*)&xv[j] = *(const float4*)(p + j);
    float s1 = 0.f, s2 = 0.f;
#pragma unroll
    for (int j = 0; j < 16; j++){ s1 += xv[j]; s2 = fmaf(xv[j], xv[j], s2); }
#pragma unroll
    for (int j = 0; j < 16; j += 4)
      *(float4*)&tile[r][q*16 + j] = *(const float4*)&xv[j];
    ps[r][q] = s1; pq[r][q] = s2;
    __syncthreads();
    if (tid < 64){
      float4 a  = *(const float4*)&ps[tid][0];
      float4 b4 = *(const float4*)&pq[tid][0];
      float m = (a.x + a.y + a.z + a.w) * (1.f/64.f);
      float v = (b4.x + b4.y + b4.z + b4.w) * (1.f/64.f) - m*m;
      mu[tid] = m;
      rs[tid] = rsqrtf(v + 1e-5f);
    }
    __syncthreads();
#pragma unroll 2
    for (int rr = 0; rr < 64; rr++){
      float acc = 0.f;
#pragma unroll
      for (int k = 0; k < HH; k += 4){
        float4 x4 = *(const float4*)&tile[rr][k];      // broadcast
        acc = fmaf(w[k],   x4.x, acc); acc = fmaf(w[k+1], x4.y, acc);
        acc = fmaf(w[k+2], x4.z, acc); acc = fmaf(w[k+3], x4.w, acc);
      }
      float o = rs[rr]*(acc - mu[rr]*wsum) + bias2;
      out[(size_t)(rowbase + rr)*VV + tid] = o;
    }
    __syncthreads();
  }
}

extern "C" void kernel_launch(void* const* d_in, const int* in_sizes, int n_in,
                              void* d_out, int out_size, void* d_ws, size_t ws_size,
                              hipStream_t stream){
  (void)in_sizes; (void)n_in; (void)out_size; (void)ws_size;
  const int*   x    = (const int*)d_in[0];
  const float* emb  = (const float*)d_in[1];
  const float* w_ih = (const float*)d_in[2];
  const float* w_hh = (const float*)d_in[3];
  const float* b_ih = (const float*)d_in[4];
  const float* b_hh = (const float*)d_in[5];
  const float* wqkv = (const float*)d_in[6];
  const float* bqkv = (const float*)d_in[7];
  const float* wo   = (const float*)d_in[8];
  const float* bo   = (const float*)d_in[9];
  const float* ln_g = (const float*)d_in[10];
  const float* ln_b = (const float*)d_in[11];
  const float* fc_w = (const float*)d_in[12];
  const float* fc_b = (const float*)d_in[13];

  char* ws = (char*)d_ws;
  float* embW = (float*)ws;                               // 256*256*4 = 256KB
  float* bufA = (float*)(ws + (1<<20));                   // 32MB fp32 (B,T,H)
  float* bufB = bufA + (size_t)BB*TT*HH;                  // 32MB fp32

  k_embw<<<VV,  256, 0, stream>>>(emb, w_ih, b_ih, b_hh, embW);
  k_lstm<<<BB,  256, 0, stream>>>(x, embW, w_hh, bufA);
  k_mha <<<TT,  256, 0, stream>>>(bufA, wqkv,          bqkv,       wo,          bo,      bufB);
  k_mha <<<TT,  256, 0, stream>>>(bufB, wqkv + 192*64, bqkv + 192, wo + 64*64,  bo + 64, bufA);
  k_fc  <<<512, 256, 0, stream>>>(bufA, ln_g, ln_b, fc_w, fc_b, (float*)d_out);
}

// Round 3
// 1774.677 us; speedup vs baseline: 1.0505x; 1.0505x over previous
//
#include <hip/hip_runtime.h>

enum { TT = 2048, HH = 64, BB = 64, GG = 256, VV = 256 };

// LDS-only barrier: does NOT drain vmcnt (global loads/stores stay in flight).
// Safe when the barrier only protects LDS traffic (CK's block_sync_lds pattern).
static __device__ __forceinline__ void bar_lds(){
  asm volatile("s_waitcnt lgkmcnt(0)\n\ts_barrier" ::: "memory");
}

// ---------------- K1: embW[v][g] = emb[v]·w_ih[g] + b_ih[g] + b_hh[g] ----------------
__global__ __launch_bounds__(256) void k_embw(const float* __restrict__ emb,
                                              const float* __restrict__ w_ih,
                                              const float* __restrict__ b_ih,
                                              const float* __restrict__ b_hh,
                                              float* __restrict__ embW){
  int v = blockIdx.x, g = threadIdx.x;
  __shared__ float e[HH];
  if (g < HH) e[g] = emb[v*HH + g];
  bar_lds();
  float acc = b_ih[g] + b_hh[g];
  const float* wr = w_ih + g*HH;
#pragma unroll
  for (int k = 0; k < HH; k += 4){
    float4 w4 = *(const float4*)(wr + k);
    acc = fmaf(e[k],   w4.x, acc); acc = fmaf(e[k+1], w4.y, acc);
    acc = fmaf(e[k+2], w4.z, acc); acc = fmaf(e[k+3], w4.w, acc);
  }
  embW[v*GG + g] = acc;
}

// ---------------- K2: LSTM, one workgroup per batch row ----------------
// thread g owns gate-row g (gate q = g>>6, element e = g&63); wave 0 owns c/h state
__global__ __launch_bounds__(256) void k_lstm(const int* __restrict__ x,
                                              const float* __restrict__ embW,
                                              const float* __restrict__ w_hh,
                                              float* __restrict__ hout){
  int b = blockIdx.x, g = threadIdx.x;
  __shared__ float hsh[HH];
  __shared__ float gsh[GG];
  float w[HH];
  {
    const float* wr = w_hh + g*HH;
#pragma unroll
    for (int k = 0; k < HH; k += 4)
      *(float4*)&w[k] = *(const float4*)(wr + k);
  }
  if (g < HH) hsh[g] = 0.f;
  float c = 0.f;
  const int* xb = x + b*TT;
  int i0 = xb[0];
  float gx = embW[i0*GG + g];          // gates(x) for t=0
  int i1 = xb[1];
  const bool istanh = ((g >> 6) == 2); // wave 2 = g-gate (tanh); wave-uniform branch
  float* houtb = hout + (size_t)b*TT*HH;
  bar_lds();
#pragma unroll 2
  for (int t = 0; t < TT; t++){
    float gxn = embW[i1*GG + g];                       // prefetch t+1 (coalesced 1KB, L2)
    int inx = xb[(t + 2 < TT) ? (t + 2) : (TT - 1)];   // prefetch index t+2
    // 4 independent fma chains over the 64-wide dot
    float a0 = 0.f, a1 = 0.f, a2 = 0.f, a3 = 0.f;
#pragma unroll
    for (int k = 0; k < 16; k += 4){
      float4 h0 = *(const float4*)&hsh[k];             // broadcast ds_read_b128
      float4 h1 = *(const float4*)&hsh[16 + k];
      float4 h2 = *(const float4*)&hsh[32 + k];
      float4 h3 = *(const float4*)&hsh[48 + k];
      a0 = fmaf(w[k],      h0.x, a0); a0 = fmaf(w[k+1],    h0.y, a0);
      a0 = fmaf(w[k+2],    h0.z, a0); a0 = fmaf(w[k+3],    h0.w, a0);
      a1 = fmaf(w[16+k],   h1.x, a1); a1 = fmaf(w[16+k+1], h1.y, a1);
      a1 = fmaf(w[16+k+2], h1.z, a1); a1 = fmaf(w[16+k+3], h1.w, a1);
      a2 = fmaf(w[32+k],   h2.x, a2); a2 = fmaf(w[32+k+1], h2.y, a2);
      a2 = fmaf(w[32+k+2], h2.z, a2); a2 = fmaf(w[32+k+3], h2.w, a2);
      a3 = fmaf(w[48+k],   h3.x, a3); a3 = fmaf(w[48+k+1], h3.y, a3);
      a3 = fmaf(w[48+k+2], h3.z, a3); a3 = fmaf(w[48+k+3], h3.w, a3);
    }
    float acc = ((a0 + a1) + (a2 + a3)) + gx;          // gx added last: load has whole phase to land
    float val;
    if (istanh) val = 1.f - 2.f/(__expf(2.f*acc) + 1.f);
    else        val = 1.f/(1.f + __expf(-acc));
    gsh[g] = val;
    bar_lds();
    if (g < HH){                                        // wave 0 only (uniform)
      float i_ = gsh[g], f_ = gsh[HH+g], gg = gsh[128+g], o_ = gsh[192+g];
      c = fmaf(f_, c, i_*gg);
      float th = 1.f - 2.f/(__expf(2.f*c) + 1.f);
      float hv = o_*th;
      hsh[g] = hv;
      houtb[(size_t)t*HH + g] = hv;                     // fire-and-forget (no vmcnt drain)
    }
    bar_lds();
    gx = gxn; i1 = inx;
  }
}

// ---------------- K3: fused MHA level, one workgroup per time step t ----------------
// attention is over the batch axis (64x64 per (t, head)); all staging in LDS (64KB)
__global__ __launch_bounds__(256) void k_mha(const float* __restrict__ hin,
                                             const float* __restrict__ wqkv,
                                             const float* __restrict__ bqkv,
                                             const float* __restrict__ wo,
                                             const float* __restrict__ bo,
                                             float* __restrict__ hout){
  int t = blockIdx.x, tid = threadIdx.x;
  __shared__ float xta[BB][HH];    // x column, later reused for attention output (16KB)
  __shared__ float qkvs[BB][192];  // qkv rows (48KB)

  // stage-2 weights (threads 0..191 own one output feature row)
  float wq[HH]; float bq = 0.f;
  if (tid < 192){
#pragma unroll
    for (int k = 0; k < HH; k += 4)
      *(float4*)&wq[k] = *(const float4*)(wqkv + tid*HH + k);
    bq = bqkv[tid];
  }
  // stage 1: load x[:, t, :] (64 rows x 64 fp32); thread loads 16 floats
  {
    int r = tid >> 2, q = tid & 3;
    const float* p = hin + (size_t)(r*TT + t)*HH + q*16;
#pragma unroll
    for (int j = 0; j < 16; j += 4)
      *(float4*)&xta[r][q*16 + j] = *(const float4*)(p + j);
  }
  bar_lds();
  // stage 2: qkv = x @ wqkv^T + bqkv
  if (tid < 192){
#pragma unroll 4
    for (int b = 0; b < BB; b++){
      float acc = bq;
#pragma unroll
      for (int k = 0; k < HH; k += 4){
        float4 xv = *(const float4*)&xta[b][k];        // broadcast
        acc = fmaf(wq[k],   xv.x, acc); acc = fmaf(wq[k+1], xv.y, acc);
        acc = fmaf(wq[k+2], xv.z, acc); acc = fmaf(wq[k+3], xv.w, acc);
      }
      qkvs[b][tid] = acc;
    }
  }
  bar_lds();
  // stage 3: attention; thread (head hd = wave, row l = lane)
  {
    int hd = tid >> 6, l = tid & 63;
    int qo = hd*16, ko = 64 + hd*16, vo = 128 + hd*16;
    float4 q0 = *(const float4*)&qkvs[l][qo];
    float4 q1 = *(const float4*)&qkvs[l][qo+4];
    float4 q2 = *(const float4*)&qkvs[l][qo+8];
    float4 q3 = *(const float4*)&qkvs[l][qo+12];
    float S[BB];
#pragma unroll
    for (int m = 0; m < BB; m++){
      float4 k0 = *(const float4*)&qkvs[m][ko];
      float4 k1 = *(const float4*)&qkvs[m][ko+4];
      float4 k2 = *(const float4*)&qkvs[m][ko+8];
      float4 k3 = *(const float4*)&qkvs[m][ko+12];
      float d;
      d = q0.x*k0.x;         d = fmaf(q0.y,k0.y,d); d = fmaf(q0.z,k0.z,d); d = fmaf(q0.w,k0.w,d);
      d = fmaf(q1.x,k1.x,d); d = fmaf(q1.y,k1.y,d); d = fmaf(q1.z,k1.z,d); d = fmaf(q1.w,k1.w,d);
      d = fmaf(q2.x,k2.x,d); d = fmaf(q2.y,k2.y,d); d = fmaf(q2.z,k2.z,d); d = fmaf(q2.w,k2.w,d);
      d = fmaf(q3.x,k3.x,d); d = fmaf(q3.y,k3.y,d); d = fmaf(q3.z,k3.z,d); d = fmaf(q3.w,k3.w,d);
      S[m] = 0.25f*d;
    }
    float mx = S[0];
#pragma unroll
    for (int m = 1; m < BB; m++) mx = fmaxf(mx, S[m]);
    float sum = 0.f;
#pragma unroll
    for (int m = 0; m < BB; m++){ S[m] = __expf(S[m] - mx); sum += S[m]; }
    float inv = 1.f/sum;
    float4 a0 = make_float4(0,0,0,0), a1 = a0, a2 = a0, a3 = a0;
#pragma unroll
    for (int m = 0; m < BB; m++){
      float s = S[m];
      float4 v0 = *(const float4*)&qkvs[m][vo];
      float4 v1 = *(const float4*)&qkvs[m][vo+4];
      float4 v2 = *(const float4*)&qkvs[m][vo+8];
      float4 v3 = *(const float4*)&qkvs[m][vo+12];
      a0.x = fmaf(s,v0.x,a0.x); a0.y = fmaf(s,v0.y,a0.y); a0.z = fmaf(s,v0.z,a0.z); a0.w = fmaf(s,v0.w,a0.w);
      a1.x = fmaf(s,v1.x,a1.x); a1.y = fmaf(s,v1.y,a1.y); a1.z = fmaf(s,v1.z,a1.z); a1.w = fmaf(s,v1.w,a1.w);
      a2.x = fmaf(s,v2.x,a2.x); a2.y = fmaf(s,v2.y,a2.y); a2.z = fmaf(s,v2.z,a2.z); a2.w = fmaf(s,v2.w,a2.w);
      a3.x = fmaf(s,v3.x,a3.x); a3.y = fmaf(s,v3.y,a3.y); a3.z = fmaf(s,v3.z,a3.z); a3.w = fmaf(s,v3.w,a3.w);
    }
    a0.x*=inv; a0.y*=inv; a0.z*=inv; a0.w*=inv;
    a1.x*=inv; a1.y*=inv; a1.z*=inv; a1.w*=inv;
    a2.x*=inv; a2.y*=inv; a2.z*=inv; a2.w*=inv;
    a3.x*=inv; a3.y*=inv; a3.z*=inv; a3.w*=inv;
    bar_lds();   // stage-2 readers of xta done before overwrite
    *(float4*)&xta[l][qo]    = a0;
    *(float4*)&xta[l][qo+4]  = a1;
    *(float4*)&xta[l][qo+8]  = a2;
    *(float4*)&xta[l][qo+12] = a3;
  }
  bar_lds();
  // stage 4: out projection; thread owns col c for 16 rows
  {
    int c = tid & 63, wg = tid >> 6;
    float wor[HH];
#pragma unroll
    for (int k = 0; k < HH; k += 4)
      *(float4*)&wor[k] = *(const float4*)(wo + c*HH + k);
    float bo4 = bo[c];
#pragma unroll 2
    for (int j = 0; j < 16; j++){
      int b = wg*16 + j;
      float acc = bo4;
#pragma unroll
      for (int k = 0; k < HH; k += 4){
        float4 xv = *(const float4*)&xta[b][k];        // broadcast
        acc = fmaf(wor[k],   xv.x, acc); acc = fmaf(wor[k+1], xv.y, acc);
        acc = fmaf(wor[k+2], xv.z, acc); acc = fmaf(wor[k+3], xv.w, acc);
      }
      hout[(size_t)(b*TT + t)*HH + c] = acc;
    }
  }
}

// ---------------- K4: LayerNorm + FC (ln folded into fc_w registers) ----------------
__global__ __launch_bounds__(256) void k_fc(const float* __restrict__ hin,
                                            const float* __restrict__ ln_g,
                                            const float* __restrict__ ln_b,
                                            const float* __restrict__ fc_w,
                                            const float* __restrict__ fc_b,
                                            float* __restrict__ out){
  int tid = threadIdx.x;
  __shared__ float tile[64][68];
  __shared__ float ps[64][4];
  __shared__ float pq[64][4];
  __shared__ float mu[64], rs[64];
  float w[HH];
  float wsum = 0.f, bias2 = fc_b[tid];
#pragma unroll
  for (int k = 0; k < HH; k += 4){
    float4 wv = *(const float4*)(fc_w + tid*HH + k);
    float4 gv = *(const float4*)(ln_g + k);
    float4 bv = *(const float4*)(ln_b + k);
    bias2 = fmaf(bv.x, wv.x, bias2); bias2 = fmaf(bv.y, wv.y, bias2);
    bias2 = fmaf(bv.z, wv.z, bias2); bias2 = fmaf(bv.w, wv.w, bias2);
    w[k]   = gv.x*wv.x; w[k+1] = gv.y*wv.y;
    w[k+2] = gv.z*wv.z; w[k+3] = gv.w*wv.w;
    wsum += w[k] + w[k+1] + w[k+2] + w[k+3];
  }
  int r = tid >> 2, q = tid & 3;
  for (int ti = 0; ti < 4; ti++){
    int rowbase = blockIdx.x*256 + ti*64;
    const float* p = hin + (size_t)(rowbase + r)*HH + q*16;
    float xv[16];
#pragma unroll
    for (int j = 0; j < 16; j += 4)
      *(float4*)&xv[j] = *(const float4*)(p + j);
    float s1 = 0.f, s2 = 0.f;
#pragma unroll
    for (int j = 0; j < 16; j++){ s1 += xv[j]; s2 = fmaf(xv[j], xv[j], s2); }
#pragma unroll
    for (int j = 0; j < 16; j += 4)
      *(float4*)&tile[r][q*16 + j] = *(const float4*)&xv[j];
    ps[r][q] = s1; pq[r][q] = s2;
    bar_lds();
    if (tid < 64){
      float4 a  = *(const float4*)&ps[tid][0];
      float4 b4 = *(const float4*)&pq[tid][0];
      float m = (a.x + a.y + a.z + a.w) * (1.f/64.f);
      float v = (b4.x + b4.y + b4.z + b4.w) * (1.f/64.f) - m*m;
      mu[tid] = m;
      rs[tid] = rsqrtf(v + 1e-5f);
    }
    bar_lds();
#pragma unroll 2
    for (int rr = 0; rr < 64; rr++){
      float acc = 0.f;
#pragma unroll
      for (int k = 0; k < HH; k += 4){
        float4 x4 = *(const float4*)&tile[rr][k];      // broadcast
        acc = fmaf(w[k],   x4.x, acc); acc = fmaf(w[k+1], x4.y, acc);
        acc = fmaf(w[k+2], x4.z, acc); acc = fmaf(w[k+3], x4.w, acc);
      }
      float o = rs[rr]*(acc - mu[rr]*wsum) + bias2;
      out[(size_t)(rowbase + rr)*VV + tid] = o;
    }
    bar_lds();
  }
}

extern "C" void kernel_launch(void* const* d_in, const int* in_sizes, int n_in,
                              void* d_out, int out_size, void* d_ws, size_t ws_size,
                              hipStream_t stream){
  (void)in_sizes; (void)n_in; (void)out_size; (void)ws_size;
  const int*   x    = (const int*)d_in[0];
  const float* emb  = (const float*)d_in[1];
  const float* w_ih = (const float*)d_in[2];
  const float* w_hh = (const float*)d_in[3];
  const float* b_ih = (const float*)d_in[4];
  const float* b_hh = (const float*)d_in[5];
  const float* wqkv = (const float*)d_in[6];
  const float* bqkv = (const float*)d_in[7];
  const float* wo   = (const float*)d_in[8];
  const float* bo   = (const float*)d_in[9];
  const float* ln_g = (const float*)d_in[10];
  const float* ln_b = (const float*)d_in[11];
  const float* fc_w = (const float*)d_in[12];
  const float* fc_b = (const float*)d_in[13];

  char* ws = (char*)d_ws;
  float* embW = (float*)ws;                               // 256*256*4 = 256KB
  float* bufA = (float*)(ws + (1<<20));                   // 32MB fp32 (B,T,H)
  float* bufB = bufA + (size_t)BB*TT*HH;                  // 32MB fp32

  k_embw<<<VV,  256, 0, stream>>>(emb, w_ih, b_ih, b_hh, embW);
  k_lstm<<<BB,  256, 0, stream>>>(x, embW, w_hh, bufA);
  k_mha <<<TT,  256, 0, stream>>>(bufA, wqkv,          bqkv,       wo,          bo,      bufB);
  k_mha <<<TT,  256, 0, stream>>>(bufB, wqkv + 192*64, bqkv + 192, wo + 64*64,  bo + 64, bufA);
  k_fc  <<<512, 256, 0, stream>>>(bufA, ln_g, ln_b, fc_w, fc_b, (float*)d_out);
}